// Round 13
// baseline (262.626 us; speedup 1.0000x reference)
//
#include <hip/hip_runtime.h>
#include <cstddef>
#include <cstdint>

typedef __attribute__((ext_vector_type(8))) short bf16x8;   // 8 bf16 = 4 VGPR
typedef __attribute__((ext_vector_type(16))) float f32x16;  // MFMA 32x32 acc

static constexpr float LN2 = 0.69314718055994530942f;
static constexpr float INV_LN2 = 1.44269504088896340736f;

__device__ __forceinline__ unsigned short f2bf(float f) {
  unsigned int u = __float_as_uint(f);
  u += 0x7fffu + ((u >> 16) & 1u);   // RNE
  return (unsigned short)(u >> 16);
}

__device__ __forceinline__ unsigned int cvt_pk_bf16(float a, float b) {
  unsigned int r;
  asm("v_cvt_pk_bf16_f32 %0, %1, %2" : "=v"(r) : "v"(a), "v"(b));
  return r;
}

__device__ __forceinline__ float hw_exp2(float x) {
  float r;
  asm("v_exp_f32 %0, %1" : "=v"(r) : "v"(x));
  return r;
}
__device__ __forceinline__ float hw_log2(float x) {
  float r;
  asm("v_log_f32 %0, %1" : "=v"(r) : "v"(x));
  return r;
}

// softplus(x)-ln2 = max(x,0)-ln2 + ln2*log2(1+2^(-|x|/ln2)); rel err ~1e-5
__device__ __forceinline__ float shsp(float x) {
  float t = hw_exp2(-fabsf(x) * INV_LN2);
  float l = hw_log2(1.0f + t);
  return fmaf(LN2, l, fmaxf(x, 0.0f) - LN2);
}

// async 16B global -> LDS (lane l writes lds + l*16)
__device__ __forceinline__ void async_copy16(const void* g, void* l) {
  __builtin_amdgcn_global_load_lds(
      (const __attribute__((address_space(1))) void*)g,
      (__attribute__((address_space(3))) void*)l, 16, 0, 0);
}

#define WAITV(N) asm volatile("s_waitcnt vmcnt(" #N ")" ::: "memory")

// ---- prep: h (N*64 f32) -> bf16 ----
__global__ void prep_h_kernel(const float* __restrict__ h,
                              unsigned short* __restrict__ hbf, int n4) {
  int i = blockIdx.x * 256 + threadIdx.x;
  if (i < n4) {
    float4 v = reinterpret_cast<const float4*>(h)[i];
    uint2 o;
    o.x = cvt_pk_bf16(v.x, v.y);
    o.y = cvt_pk_bf16(v.z, v.w);
    reinterpret_cast<uint2*>(hbf)[i] = o;
  }
}

// ---- prep: pack W1^T, W2^T into MFMA-fragment order (bf16), kk-major ----
__global__ void prep_w_kernel(const float* __restrict__ W1,
                              const float* __restrict__ W2,
                              unsigned short* __restrict__ Wp1,
                              unsigned short* __restrict__ Wp2) {
  int j = blockIdx.x * 256 + threadIdx.x;
  if (j < 48 * 64) {
    int f  = j / 64;
    int l  = j % 64;
    int kk = f >> 2;
    int mt = f & 3;
    int col = mt * 32 + (l & 31);
    int kb  = kk * 16 + (l >> 5) * 8;
    #pragma unroll
    for (int i = 0; i < 8; ++i)
      Wp1[(size_t)j * 8 + i] = f2bf(W1[(size_t)(kb + i) * 128 + col]);
  } else if (j < 48 * 64 + 16 * 64) {
    int jj = j - 48 * 64;
    int f  = jj / 64;
    int l  = jj % 64;
    int kk = f >> 1;
    int mt = f & 1;
    int oc = mt * 32 + (l & 31);
    int kb = kk * 16 + (l >> 5) * 8;
    #pragma unroll
    for (int i = 0; i < 8; ++i)
      Wp2[(size_t)jj * 8 + i] = f2bf(W2[(size_t)(kb + i) * 64 + oc]);
  }
}

// ---- main fused kernel: R12 + const-load stall removal + setprio ----
// 448 threads (7 waves), 1 block/CU. LDS 160K = W1L 48K + 7 x 16K h-dbuf.
// New vs R12: b1/b2 pre-loaded once as f32x16 C-init regs (kk=0 MFMA takes
// them as C-in: zero per-tile bias loads/adds); W2 frags loaded to regs
// right after GEMM1 (L1 latency hidden under epi1); ea(t+1) moved after
// GEMM2 (caps live regs); s_setprio(1) around MFMA clusters.
// WAITV(8) anchor unchanged: the 8 out-stores are always the youngest vmem.
__global__ __launch_bounds__(448, 1)
void edge_mlp_kernel(const float* __restrict__ ea,
                     const int* __restrict__ eidx,
                     const float* __restrict__ b1,
                     const float* __restrict__ b2,
                     const unsigned short* __restrict__ hbf,
                     const unsigned short* __restrict__ Wp1,
                     const unsigned short* __restrict__ Wp2,
                     float* __restrict__ out,
                     int E, int ntiles) {
  __shared__ __align__(16) unsigned char LDS[163840];

  const int tid  = threadIdx.x;
  const int lane = tid & 63;
  const int w    = tid >> 6;          // 0..6
  const int lo   = lane & 31;
  const int hi   = lane >> 5;
  const int rsw  = lo & 7;
  const int lr4  = lane >> 4;         // staging row-within-4
  const int p    = lane & 15;         // staging chunk position

  unsigned char* W1L = LDS;
  unsigned char* HA0 = LDS + 49152 + w * 16384;   // 2 x 8K dbuf

  // ---- stage W1 into LDS once (48KB = 48 groups of 64 chunks) ----
  #pragma unroll
  for (int j = 0; j < 7; ++j) {
    int grp = j * 7 + w;
    if (grp < 48) {
      int ch = grp * 64;
      async_copy16(Wp1 + (size_t)(ch + lane) * 8, LDS + ch * 16);
    }
  }

  // ---- biases -> C-init registers (once) ----
  f32x16 b1i[4];
  #pragma unroll
  for (int mt = 0; mt < 4; ++mt) {
    #pragma unroll
    for (int g = 0; g < 4; ++g) {
      float4 bb = *reinterpret_cast<const float4*>(b1 + mt * 32 + g * 8 + hi * 4);
      b1i[mt][g * 4 + 0] = bb.x;
      b1i[mt][g * 4 + 1] = bb.y;
      b1i[mt][g * 4 + 2] = bb.z;
      b1i[mt][g * 4 + 3] = bb.w;
    }
  }
  f32x16 b2i[2];
  #pragma unroll
  for (int mt = 0; mt < 2; ++mt) {
    #pragma unroll
    for (int g = 0; g < 4; ++g) {
      float4 bb = *reinterpret_cast<const float4*>(b2 + mt * 32 + g * 8 + hi * 4);
      b2i[mt][g * 4 + 0] = bb.x;
      b2i[mt][g * 4 + 1] = bb.y;
      b2i[mt][g * 4 + 2] = bb.z;
      b2i[mt][g * 4 + 3] = bb.w;
    }
  }

  __syncthreads();                      // once; drains vmcnt

  const int gw     = blockIdx.x * 7 + w;
  const int nwaves = gridDim.x * 7;

  float4 eareg[8];
  int nodeN = 0, nodeN2 = 0;

#define LOADIDX(t) eidx[(size_t)(lane & 1) * E + (size_t)(t) * 32 + (lane >> 1)]

#define LOADEA(t) { \
  const float* eab_ = ea + (size_t)((t) * 32 + lo) * 64; \
  _Pragma("unroll") for (int j = 0; j < 4; ++j) { \
    eareg[2 * j]     = *reinterpret_cast<const float4*>(eab_ + j * 16 + hi * 8); \
    eareg[2 * j + 1] = *reinterpret_cast<const float4*>(eab_ + j * 16 + hi * 8 + 4); \
  } }

#define ISSUE_H(NODE, HBASE) { \
  _Pragma("unroll") for (int it = 0; it < 8; ++it) { \
    int r_ = it * 4 + lr4; \
    int c_ = p ^ (r_ & 7); \
    int nd_ = __shfl(NODE, r_ * 2 + (c_ >> 3), 64); \
    async_copy16(hbf + (size_t)nd_ * 64 + (c_ & 7) * 8, (HBASE) + it * 1024); \
  } }

  // ---- prologue ----
  int t = gw;
  if (t < ntiles) {
    LOADEA(t)
    int node0 = LOADIDX(t);
    ISSUE_H(node0, HA0)
    if (t + nwaves < ntiles) nodeN = LOADIDX(t + nwaves);
    WAITV(0);
  }

  int cur = 0;
  for (; t < ntiles; t += nwaves) {
    unsigned char* HAc = HA0 + cur * 8192;
    unsigned char* HAn = HA0 + (cur ^ 1) * 8192;
    const int eb  = t * 32;
    const int tn  = t + nwaves;
    const int tnn = tn + nwaves;

    WAITV(8);                           // h(t) retired (stores(t-1) youngest 8)

    if (tn < ntiles)  { ISSUE_H(nodeN, HAn) }    // h(t+1) async
    if (tnn < ntiles) { nodeN2 = LOADIDX(tnn); }

    // ---- GEMM1: x^T = W1^T(128x192) @ concat^T; C-init = b1 ----
    f32x16 acc[4];
    __builtin_amdgcn_s_setprio(1);
    #pragma unroll
    for (int kk = 0; kk < 12; ++kk) {
      bf16x8 bfr;
      if (kk < 8) {
        bfr = *reinterpret_cast<const bf16x8*>(
            HAc + lo * 256 + (((kk * 2 + hi) ^ rsw) * 16));
      } else {
        float4 lo4 = eareg[(kk - 8) * 2];
        float4 hi4 = eareg[(kk - 8) * 2 + 1];
        union { bf16x8 v; unsigned u[4]; } tt;
        tt.u[0] = cvt_pk_bf16(lo4.x, lo4.y);
        tt.u[1] = cvt_pk_bf16(lo4.z, lo4.w);
        tt.u[2] = cvt_pk_bf16(hi4.x, hi4.y);
        tt.u[3] = cvt_pk_bf16(hi4.z, hi4.w);
        bfr = tt.v;
      }
      #pragma unroll
      for (int mt = 0; mt < 4; ++mt) {
        bf16x8 afr = *reinterpret_cast<const bf16x8*>(
            W1L + (size_t)(kk * 4 + mt) * 1024 + lane * 16);
        acc[mt] = __builtin_amdgcn_mfma_f32_32x32x16_bf16(
            afr, bfr, (kk == 0) ? b1i[mt] : acc[mt], 0, 0, 0);
      }
    }
    __builtin_amdgcn_s_setprio(0);

    // ---- W2 frags -> registers now; consumed ~epi1 later (latency hidden) ----
    bf16x8 w2f[16];
    #pragma unroll
    for (int kk = 0; kk < 8; ++kk) {
      #pragma unroll
      for (int mt = 0; mt < 2; ++mt) {
        w2f[kk * 2 + mt] = *reinterpret_cast<const bf16x8*>(
            Wp2 + ((size_t)(kk * 2 + mt) * 64 + lane) * 8);
      }
    }

    // ---- epilogue 1: softplus (bias already in acc), pack bf16 ----
    unsigned u0[16], u1[16];
    #pragma unroll
    for (int c = 0; c < 16; ++c) {
      int mt = c >> 2, g = c & 3;
      float s0 = shsp(acc[mt][g * 4 + 0]);
      float s1 = shsp(acc[mt][g * 4 + 1]);
      float s2 = shsp(acc[mt][g * 4 + 2]);
      float s3 = shsp(acc[mt][g * 4 + 3]);
      u0[c] = cvt_pk_bf16(s0, s1);
      u1[c] = cvt_pk_bf16(s2, s3);
    }

    // ---- half-exchange lane <-> lane^32 (R6-verified) -> GEMM2 B-frags ----
    unsigned pa[8][4];
    #pragma unroll
    for (int kk = 0; kk < 8; ++kk) {
      unsigned x0 = u0[2 * kk], y0 = u0[2 * kk + 1];
      unsigned x1 = u1[2 * kk], y1 = u1[2 * kk + 1];
      unsigned s0 = hi ? x0 : y0;
      unsigned s1 = hi ? x1 : y1;
      unsigned t0 = (unsigned)__shfl_xor((int)s0, 32, 64);
      unsigned t1 = (unsigned)__shfl_xor((int)s1, 32, 64);
      pa[kk][0] = hi ? t0 : x0;
      pa[kk][1] = hi ? t1 : x1;
      pa[kk][2] = hi ? y0 : t0;
      pa[kk][3] = hi ? y1 : t1;
    }

    // ---- GEMM2: out^T = W2^T(64x128) @ x; C-init = b2; W2 from regs ----
    f32x16 acc2[2];
    __builtin_amdgcn_s_setprio(1);
    #pragma unroll
    for (int kk = 0; kk < 8; ++kk) {
      union { bf16x8 v; unsigned u[4]; } tt;
      tt.u[0] = pa[kk][0];
      tt.u[1] = pa[kk][1];
      tt.u[2] = pa[kk][2];
      tt.u[3] = pa[kk][3];
      #pragma unroll
      for (int mt = 0; mt < 2; ++mt) {
        acc2[mt] = __builtin_amdgcn_mfma_f32_32x32x16_bf16(
            w2f[kk * 2 + mt], tt.v, (kk == 0) ? b2i[mt] : acc2[mt], 0, 0, 0);
      }
    }
    __builtin_amdgcn_s_setprio(0);

    // ea(t+1) -> VGPRs (after GEMM2: caps live regs; ~full tile to land)
    if (tn < ntiles) { LOADEA(tn) }

    // ---- epilogue 2: f32 out rows into HAc (h dead after GEMM1) ----
    #pragma unroll
    for (int mt = 0; mt < 2; ++mt) {
      #pragma unroll
      for (int g = 0; g < 4; ++g) {
        float4 o;
        o.x = acc2[mt][g * 4 + 0];
        o.y = acc2[mt][g * 4 + 1];
        o.z = acc2[mt][g * 4 + 2];
        o.w = acc2[mt][g * 4 + 3];
        int c = mt * 8 + g * 2 + hi;          // 16B f32 chunk index
        *reinterpret_cast<float4*>(HAc + lo * 256 + ((c ^ rsw) * 16)) = o;
      }
    }

    // ---- coalesced stores: exactly 8 global_store_dwordx4 (WAITV anchor) ----
    #pragma unroll
    for (int it = 0; it < 8; ++it) {
      int r = it * 4 + lr4;
      float4 v = *reinterpret_cast<const float4*>(HAc + r * 256 + p * 16);
      int c = p ^ (r & 7);
      *reinterpret_cast<float4*>(out + (size_t)(eb + r) * 64 + c * 4) = v;
    }

    nodeN = nodeN2;
    cur ^= 1;
  }
}

extern "C" void kernel_launch(void* const* d_in, const int* in_sizes, int n_in,
                              void* d_out, int out_size, void* d_ws, size_t ws_size,
                              hipStream_t stream) {
  const float* h  = (const float*)d_in[0];
  const float* ea = (const float*)d_in[1];
  const int*  idx = (const int*)d_in[2];
  const float* W1 = (const float*)d_in[3];
  const float* b1 = (const float*)d_in[4];
  const float* W2 = (const float*)d_in[5];
  const float* b2 = (const float*)d_in[6];
  float* out = (float*)d_out;

  const int N = in_sizes[0] / 64;      // 50000
  const int E = in_sizes[1] / 64;      // 800000

  unsigned short* hbf = (unsigned short*)d_ws;                       // N*64 bf16
  size_t off1 = (size_t)N * 64 * 2;
  unsigned short* Wp1 = (unsigned short*)((char*)d_ws + off1);       // 24576 bf16
  unsigned short* Wp2 = (unsigned short*)((char*)d_ws + off1 + 24576 * 2);

  int n4 = (N * 64) / 4;
  prep_h_kernel<<<(n4 + 255) / 256, 256, 0, stream>>>(h, hbf, n4);
  prep_w_kernel<<<16, 256, 0, stream>>>(W1, W2, Wp1, Wp2);

  int ntiles = E / 32;                  // 25000 wave-tiles
  edge_mlp_kernel<<<256, 448, 0, stream>>>(ea, idx, b1, b2, hbf, Wp1, Wp2,
                                           out, E, ntiles);
}

// Round 14
// 157.588 us; speedup vs baseline: 1.6665x; 1.6665x over previous
//
#include <hip/hip_runtime.h>
#include <cstddef>
#include <cstdint>

typedef __attribute__((ext_vector_type(8))) short bf16x8;   // 8 bf16 = 4 VGPR
typedef __attribute__((ext_vector_type(16))) float f32x16;  // MFMA 32x32 acc

static constexpr float LN2 = 0.69314718055994530942f;
static constexpr float INV_LN2 = 1.44269504088896340736f;

__device__ __forceinline__ unsigned short f2bf(float f) {
  unsigned int u = __float_as_uint(f);
  u += 0x7fffu + ((u >> 16) & 1u);   // RNE
  return (unsigned short)(u >> 16);
}

__device__ __forceinline__ unsigned int cvt_pk_bf16(float a, float b) {
  unsigned int r;
  asm("v_cvt_pk_bf16_f32 %0, %1, %2" : "=v"(r) : "v"(a), "v"(b));
  return r;
}

__device__ __forceinline__ float hw_exp2(float x) {
  float r;
  asm("v_exp_f32 %0, %1" : "=v"(r) : "v"(x));
  return r;
}
__device__ __forceinline__ float hw_log2(float x) {
  float r;
  asm("v_log_f32 %0, %1" : "=v"(r) : "v"(x));
  return r;
}

// softplus(x)-ln2 = max(x,0)-ln2 + ln2*log2(1+2^(-|x|/ln2)); rel err ~1e-5
__device__ __forceinline__ float shsp(float x) {
  float t = hw_exp2(-fabsf(x) * INV_LN2);
  float l = hw_log2(1.0f + t);
  return fmaf(LN2, l, fmaxf(x, 0.0f) - LN2);
}

// async 16B global -> LDS (lane l writes lds + l*16)
__device__ __forceinline__ void async_copy16(const void* g, void* l) {
  __builtin_amdgcn_global_load_lds(
      (const __attribute__((address_space(1))) void*)g,
      (__attribute__((address_space(3))) void*)l, 16, 0, 0);
}

#define WAITV(N) asm volatile("s_waitcnt vmcnt(" #N ")" ::: "memory")

// ---- prep: h (N*64 f32) -> bf16 ----
__global__ void prep_h_kernel(const float* __restrict__ h,
                              unsigned short* __restrict__ hbf, int n4) {
  int i = blockIdx.x * 256 + threadIdx.x;
  if (i < n4) {
    float4 v = reinterpret_cast<const float4*>(h)[i];
    uint2 o;
    o.x = cvt_pk_bf16(v.x, v.y);
    o.y = cvt_pk_bf16(v.z, v.w);
    reinterpret_cast<uint2*>(hbf)[i] = o;
  }
}

// ---- prep: pack W1^T, W2^T into MFMA-fragment order (bf16), kk-major ----
// Wp1/Wp2 are CONTIGUOUS in d_ws: chunks 0..3071 = W1, 3072..4095 = W2.
__global__ void prep_w_kernel(const float* __restrict__ W1,
                              const float* __restrict__ W2,
                              unsigned short* __restrict__ Wp1,
                              unsigned short* __restrict__ Wp2) {
  int j = blockIdx.x * 256 + threadIdx.x;
  if (j < 48 * 64) {
    int f  = j / 64;
    int l  = j % 64;
    int kk = f >> 2;
    int mt = f & 3;
    int col = mt * 32 + (l & 31);
    int kb  = kk * 16 + (l >> 5) * 8;
    #pragma unroll
    for (int i = 0; i < 8; ++i)
      Wp1[(size_t)j * 8 + i] = f2bf(W1[(size_t)(kb + i) * 128 + col]);
  } else if (j < 48 * 64 + 16 * 64) {
    int jj = j - 48 * 64;
    int f  = jj / 64;
    int l  = jj % 64;
    int kk = f >> 1;
    int mt = f & 1;
    int oc = mt * 32 + (l & 31);
    int kb = kk * 16 + (l >> 5) * 8;
    #pragma unroll
    for (int i = 0; i < 8; ++i)
      Wp2[(size_t)jj * 8 + i] = f2bf(W2[(size_t)(kb + i) * 64 + oc]);
  }
}

// ---- main fused kernel: R12 pipeline + W2-in-LDS (6 waves) + setprio ----
// 384 threads (6 waves), 1 block/CU. LDS 160K = W1L 48K + W2L 16K +
// 6 x 16K h-dbuf. vs R12: GEMM2 A-frags now ds_reads (removes 16 per-tile
// L2-latency global loads — the largest uncovered stall); one fewer wave.
// WAITV(8) anchor unchanged: the 8 out-stores are always the youngest vmem.
__global__ __launch_bounds__(384, 1)
void edge_mlp_kernel(const float* __restrict__ ea,
                     const int* __restrict__ eidx,
                     const float* __restrict__ b1,
                     const float* __restrict__ b2,
                     const unsigned short* __restrict__ hbf,
                     const unsigned short* __restrict__ Wp1,
                     float* __restrict__ out,
                     int E, int ntiles) {
  __shared__ __align__(16) unsigned char LDS[163840];

  const int tid  = threadIdx.x;
  const int lane = tid & 63;
  const int w    = tid >> 6;          // 0..5
  const int lo   = lane & 31;
  const int hi   = lane >> 5;
  const int rsw  = lo & 7;
  const int lr4  = lane >> 4;         // staging row-within-4
  const int p    = lane & 15;         // staging chunk position

  unsigned char* W1L = LDS;                        // 48K: frags 0..47
  unsigned char* W2L = LDS + 49152;                // 16K: frags 0..15
  unsigned char* HA0 = LDS + 65536 + w * 16384;    // 2 x 8K dbuf

  // ---- stage W1+W2 into LDS once (64KB = 4096 chunks; Wp1||Wp2 contig) ----
  #pragma unroll
  for (int j = 0; j < 10; ++j) {
    int ch = j * 384 + w * 64;
    async_copy16(Wp1 + (size_t)(ch + lane) * 8, LDS + ch * 16);
  }
  if (w < 4) {
    int ch = 3840 + w * 64;
    async_copy16(Wp1 + (size_t)(ch + lane) * 8, LDS + ch * 16);
  }
  __syncthreads();                      // once; drains vmcnt

  const int gw     = blockIdx.x * 6 + w;
  const int nwaves = gridDim.x * 6;

  float4 eareg[8];
  int nodeN = 0, nodeN2 = 0;

#define LOADIDX(t) eidx[(size_t)(lane & 1) * E + (size_t)(t) * 32 + (lane >> 1)]

#define LOADEA(t) { \
  const float* eab_ = ea + (size_t)((t) * 32 + lo) * 64; \
  _Pragma("unroll") for (int j = 0; j < 4; ++j) { \
    eareg[2 * j]     = *reinterpret_cast<const float4*>(eab_ + j * 16 + hi * 8); \
    eareg[2 * j + 1] = *reinterpret_cast<const float4*>(eab_ + j * 16 + hi * 8 + 4); \
  } }

#define ISSUE_H(NODE, HBASE) { \
  _Pragma("unroll") for (int it = 0; it < 8; ++it) { \
    int r_ = it * 4 + lr4; \
    int c_ = p ^ (r_ & 7); \
    int nd_ = __shfl(NODE, r_ * 2 + (c_ >> 3), 64); \
    async_copy16(hbf + (size_t)nd_ * 64 + (c_ & 7) * 8, (HBASE) + it * 1024); \
  } }

  // ---- prologue ----
  int t = gw;
  if (t < ntiles) {
    LOADEA(t)
    int node0 = LOADIDX(t);
    ISSUE_H(node0, HA0)
    if (t + nwaves < ntiles) nodeN = LOADIDX(t + nwaves);
    WAITV(0);
  }

  int cur = 0;
  for (; t < ntiles; t += nwaves) {
    unsigned char* HAc = HA0 + cur * 8192;
    unsigned char* HAn = HA0 + (cur ^ 1) * 8192;
    const int eb  = t * 32;
    const int tn  = t + nwaves;
    const int tnn = tn + nwaves;

    WAITV(8);                           // h(t) retired (stores(t-1) youngest 8)

    if (tn < ntiles)  { ISSUE_H(nodeN, HAn) }    // h(t+1) async
    if (tnn < ntiles) { nodeN2 = LOADIDX(tnn); }

    // ---- GEMM1: x^T = W1^T(128x192) @ concat^T ----
    f32x16 acc[4];
    #pragma unroll
    for (int m = 0; m < 4; ++m) acc[m] = (f32x16)0.0f;

    __builtin_amdgcn_s_setprio(1);
    #pragma unroll
    for (int kk = 0; kk < 12; ++kk) {
      bf16x8 bfr;
      if (kk < 8) {
        bfr = *reinterpret_cast<const bf16x8*>(
            HAc + lo * 256 + (((kk * 2 + hi) ^ rsw) * 16));
      } else {
        float4 lo4 = eareg[(kk - 8) * 2];
        float4 hi4 = eareg[(kk - 8) * 2 + 1];
        union { bf16x8 v; unsigned u[4]; } tt;
        tt.u[0] = cvt_pk_bf16(lo4.x, lo4.y);
        tt.u[1] = cvt_pk_bf16(lo4.z, lo4.w);
        tt.u[2] = cvt_pk_bf16(hi4.x, hi4.y);
        tt.u[3] = cvt_pk_bf16(hi4.z, hi4.w);
        bfr = tt.v;
      }
      #pragma unroll
      for (int mt = 0; mt < 4; ++mt) {
        bf16x8 afr = *reinterpret_cast<const bf16x8*>(
            W1L + (size_t)(kk * 4 + mt) * 1024 + lane * 16);
        acc[mt] = __builtin_amdgcn_mfma_f32_32x32x16_bf16(afr, bfr, acc[mt], 0, 0, 0);
      }
    }
    __builtin_amdgcn_s_setprio(0);

    // ea(t+1) -> VGPRs (overlaps epi/GEMM2/stores; eareg free after GEMM1)
    if (tn < ntiles) { LOADEA(tn) }

    // ---- epilogue 1: bias + softplus, packed bf16 in-register ----
    unsigned u0[16], u1[16];
    #pragma unroll
    for (int c = 0; c < 16; ++c) {
      int mt = c >> 2, g = c & 3;
      int f0 = mt * 32 + g * 8 + hi * 4;
      float4 bb = *reinterpret_cast<const float4*>(b1 + f0);
      float s0 = shsp(acc[mt][g * 4 + 0] + bb.x);
      float s1 = shsp(acc[mt][g * 4 + 1] + bb.y);
      float s2 = shsp(acc[mt][g * 4 + 2] + bb.z);
      float s3 = shsp(acc[mt][g * 4 + 3] + bb.w);
      u0[c] = cvt_pk_bf16(s0, s1);
      u1[c] = cvt_pk_bf16(s2, s3);
    }

    // ---- half-exchange lane <-> lane^32 (R6-verified) -> GEMM2 B-frags ----
    unsigned pa[8][4];
    #pragma unroll
    for (int kk = 0; kk < 8; ++kk) {
      unsigned x0 = u0[2 * kk], y0 = u0[2 * kk + 1];
      unsigned x1 = u1[2 * kk], y1 = u1[2 * kk + 1];
      unsigned s0 = hi ? x0 : y0;
      unsigned s1 = hi ? x1 : y1;
      unsigned t0 = (unsigned)__shfl_xor((int)s0, 32, 64);
      unsigned t1 = (unsigned)__shfl_xor((int)s1, 32, 64);
      pa[kk][0] = hi ? t0 : x0;
      pa[kk][1] = hi ? t1 : x1;
      pa[kk][2] = hi ? y0 : t0;
      pa[kk][3] = hi ? y1 : t1;
    }

    // ---- GEMM2: out^T = W2^T(64x128) @ x; W2 frags from LDS ----
    f32x16 acc2[2];
    #pragma unroll
    for (int m = 0; m < 2; ++m) acc2[m] = (f32x16)0.0f;

    __builtin_amdgcn_s_setprio(1);
    #pragma unroll
    for (int kk = 0; kk < 8; ++kk) {
      union { bf16x8 v; unsigned u[4]; } tt;
      tt.u[0] = pa[kk][0];
      tt.u[1] = pa[kk][1];
      tt.u[2] = pa[kk][2];
      tt.u[3] = pa[kk][3];
      #pragma unroll
      for (int mt = 0; mt < 2; ++mt) {
        bf16x8 afr = *reinterpret_cast<const bf16x8*>(
            W2L + (size_t)(kk * 2 + mt) * 1024 + lane * 16);
        acc2[mt] = __builtin_amdgcn_mfma_f32_32x32x16_bf16(afr, tt.v, acc2[mt], 0, 0, 0);
      }
    }
    __builtin_amdgcn_s_setprio(0);

    // ---- epilogue 2: bias -> f32 out rows into HAc (h dead after GEMM1) ----
    #pragma unroll
    for (int mt = 0; mt < 2; ++mt) {
      #pragma unroll
      for (int g = 0; g < 4; ++g) {
        int oc0 = mt * 32 + g * 8 + hi * 4;
        float4 bb = *reinterpret_cast<const float4*>(b2 + oc0);
        float4 o;
        o.x = acc2[mt][g * 4 + 0] + bb.x;
        o.y = acc2[mt][g * 4 + 1] + bb.y;
        o.z = acc2[mt][g * 4 + 2] + bb.z;
        o.w = acc2[mt][g * 4 + 3] + bb.w;
        int c = mt * 8 + g * 2 + hi;          // 16B f32 chunk index
        *reinterpret_cast<float4*>(HAc + lo * 256 + ((c ^ rsw) * 16)) = o;
      }
    }

    // ---- coalesced stores: exactly 8 global_store_dwordx4 (WAITV anchor) ----
    #pragma unroll
    for (int it = 0; it < 8; ++it) {
      int r = it * 4 + lr4;
      float4 v = *reinterpret_cast<const float4*>(HAc + r * 256 + p * 16);
      int c = p ^ (r & 7);
      *reinterpret_cast<float4*>(out + (size_t)(eb + r) * 64 + c * 4) = v;
    }

    nodeN = nodeN2;
    cur ^= 1;
  }
}

extern "C" void kernel_launch(void* const* d_in, const int* in_sizes, int n_in,
                              void* d_out, int out_size, void* d_ws, size_t ws_size,
                              hipStream_t stream) {
  const float* h  = (const float*)d_in[0];
  const float* ea = (const float*)d_in[1];
  const int*  idx = (const int*)d_in[2];
  const float* W1 = (const float*)d_in[3];
  const float* b1 = (const float*)d_in[4];
  const float* W2 = (const float*)d_in[5];
  const float* b2 = (const float*)d_in[6];
  float* out = (float*)d_out;

  const int N = in_sizes[0] / 64;      // 50000
  const int E = in_sizes[1] / 64;      // 800000

  unsigned short* hbf = (unsigned short*)d_ws;                       // N*64 bf16
  size_t off1 = (size_t)N * 64 * 2;
  unsigned short* Wp1 = (unsigned short*)((char*)d_ws + off1);       // 24576 bf16
  unsigned short* Wp2 = Wp1 + 24576;                                 // contiguous

  int n4 = (N * 64) / 4;
  prep_h_kernel<<<(n4 + 255) / 256, 256, 0, stream>>>(h, hbf, n4);
  prep_w_kernel<<<16, 256, 0, stream>>>(W1, W2, Wp1, Wp2);

  int ntiles = E / 32;                  // 25000 wave-tiles
  edge_mlp_kernel<<<256, 384, 0, stream>>>(ea, idx, b1, b2, hbf, Wp1,
                                           out, E, ntiles);
}

// Round 15
// 121.878 us; speedup vs baseline: 2.1548x; 1.2930x over previous
//
#include <hip/hip_runtime.h>
#include <cstddef>
#include <cstdint>

typedef __attribute__((ext_vector_type(8))) short bf16x8;   // 8 bf16 = 4 VGPR
typedef __attribute__((ext_vector_type(16))) float f32x16;  // MFMA 32x32 acc

static constexpr float LN2 = 0.69314718055994530942f;
static constexpr float INV_LN2 = 1.44269504088896340736f;

__device__ __forceinline__ unsigned short f2bf(float f) {
  unsigned int u = __float_as_uint(f);
  u += 0x7fffu + ((u >> 16) & 1u);   // RNE
  return (unsigned short)(u >> 16);
}

__device__ __forceinline__ unsigned int cvt_pk_bf16(float a, float b) {
  unsigned int r;
  asm("v_cvt_pk_bf16_f32 %0, %1, %2" : "=v"(r) : "v"(a), "v"(b));
  return r;
}

__device__ __forceinline__ float hw_exp2(float x) {
  float r;
  asm("v_exp_f32 %0, %1" : "=v"(r) : "v"(x));
  return r;
}
__device__ __forceinline__ float hw_log2(float x) {
  float r;
  asm("v_log_f32 %0, %1" : "=v"(r) : "v"(x));
  return r;
}

// softplus(x)-ln2 = max(x,0)-ln2 + ln2*log2(1+2^(-|x|/ln2)); rel err ~1e-5
__device__ __forceinline__ float shsp(float x) {
  float t = hw_exp2(-fabsf(x) * INV_LN2);
  float l = hw_log2(1.0f + t);
  return fmaf(LN2, l, fmaxf(x, 0.0f) - LN2);
}

// async 16B global -> LDS (lane l writes lds + l*16)
__device__ __forceinline__ void async_copy16(const void* g, void* l) {
  __builtin_amdgcn_global_load_lds(
      (const __attribute__((address_space(1))) void*)g,
      (__attribute__((address_space(3))) void*)l, 16, 0, 0);
}

#define WAITV(N) asm volatile("s_waitcnt vmcnt(" #N ")" ::: "memory")

// ---- prep: h (N*64 f32) -> bf16 ----
__global__ void prep_h_kernel(const float* __restrict__ h,
                              unsigned short* __restrict__ hbf, int n4) {
  int i = blockIdx.x * 256 + threadIdx.x;
  if (i < n4) {
    float4 v = reinterpret_cast<const float4*>(h)[i];
    uint2 o;
    o.x = cvt_pk_bf16(v.x, v.y);
    o.y = cvt_pk_bf16(v.z, v.w);
    reinterpret_cast<uint2*>(hbf)[i] = o;
  }
}

// ---- prep: pack W1^T, W2^T into MFMA-fragment order (bf16), kk-major ----
// Wp1/Wp2 CONTIGUOUS in d_ws: chunks 0..3071 = W1, 3072..4095 = W2.
__global__ void prep_w_kernel(const float* __restrict__ W1,
                              const float* __restrict__ W2,
                              unsigned short* __restrict__ Wp1,
                              unsigned short* __restrict__ Wp2) {
  int j = blockIdx.x * 256 + threadIdx.x;
  if (j < 48 * 64) {
    int f  = j / 64;
    int l  = j % 64;
    int kk = f >> 2;
    int mt = f & 3;
    int col = mt * 32 + (l & 31);
    int kb  = kk * 16 + (l >> 5) * 8;
    #pragma unroll
    for (int i = 0; i < 8; ++i)
      Wp1[(size_t)j * 8 + i] = f2bf(W1[(size_t)(kb + i) * 128 + col]);
  } else if (j < 48 * 64 + 16 * 64) {
    int jj = j - 48 * 64;
    int f  = jj / 64;
    int l  = jj % 64;
    int kk = f >> 1;
    int mt = f & 1;
    int oc = mt * 32 + (l & 31);
    int kb = kk * 16 + (l >> 5) * 8;
    #pragma unroll
    for (int i = 0; i < 8; ++i)
      Wp2[(size_t)jj * 8 + i] = f2bf(W2[(size_t)(kb + i) * 64 + oc]);
  }
}

// ---- main fused kernel: 8 pipelined waves, W1+W2+biases in LDS ----
// 512 threads (8 waves, 2/SIMD), 1 block/CU. LDS ~129K:
//   [0,48K) W1 frags; [48K,64K) W2 frags; [64K,128K) 8 x 8K h1-dbuf
//   (4K/buffer: 32 rows x 128B, src-swizzled); [128K,+768B) b1|b2 f32.
// Per-lane VGPR state: eareg[8] (ea rows), h2reg[4] (h[dst] frags, R6
//   mapping chunk 2kk+hi). Out-tile transposed through HAc in two 4K
//   passes (DS pipe in-order per wave => safe alias).
// Counted anchor: per tile, in order: H1[4] IDX1[1] IDX2[1] EA[8] H2[4]
//   STa[4] STb[4] — all issues unconditional (clamped) => uniform counts.
//   WAITV(22) at tile top retires exactly H1(t); b1/b2/W2 reads are LDS
//   (lgkm) so no stray vmcnt ops exist in the loop.
__global__ __launch_bounds__(512, 1)
void edge_mlp_kernel(const float* __restrict__ ea,
                     const int* __restrict__ eidx,
                     const float* __restrict__ b1,
                     const float* __restrict__ b2,
                     const unsigned short* __restrict__ hbf,
                     const unsigned short* __restrict__ Wp1,
                     float* __restrict__ out,
                     int E, int ntiles) {
  __shared__ __align__(16) unsigned char LDS[131840];

  const int tid  = threadIdx.x;
  const int lane = tid & 63;
  const int w    = tid >> 6;          // 0..7
  const int lo   = lane & 31;
  const int hi   = lane >> 5;
  const int rsw  = lo & 7;
  const int l8   = lane >> 3;         // staging row-within-8
  const int p    = lane & 7;          // staging chunk position (8/row)

  unsigned char* W1L = LDS;                        // 48K: frags 0..47
  unsigned char* W2L = LDS + 49152;                // 16K: frags 0..15
  unsigned char* HA0 = LDS + 65536 + w * 8192;     // 2 x 4K dbuf
  float*         BL1 = reinterpret_cast<float*>(LDS + 131072);        // 128 f32
  float*         BL2 = reinterpret_cast<float*>(LDS + 131072 + 512);  // 64 f32

  // ---- stage W1+W2 into LDS once (64KB = 4096 chunks; Wp1||Wp2 contig) ----
  #pragma unroll
  for (int j = 0; j < 8; ++j) {
    int ch = j * 512 + w * 64;
    async_copy16(Wp1 + (size_t)(ch + lane) * 8, LDS + ch * 16);
  }
  // ---- biases -> LDS (off the vmcnt path forever after) ----
  if (tid < 32) {
    float4 v = reinterpret_cast<const float4*>(b1)[tid];
    reinterpret_cast<float4*>(BL1)[tid] = v;
  } else if (tid < 48) {
    float4 v = reinterpret_cast<const float4*>(b2)[tid - 32];
    reinterpret_cast<float4*>(BL2)[tid - 32] = v;
  }
  __syncthreads();                      // once; drains vmcnt

  const int gw     = blockIdx.x * 8 + w;
  const int nwaves = gridDim.x * 8;
  const int tmax   = ntiles - 1;

  float4 eareg[8];
  bf16x8 h2reg[4];
  int nodeN1 = 0;

#define IDX1(t) eidx[(size_t)(t) * 32 + lo]
#define IDX2(t) eidx[(size_t)E + (size_t)(t) * 32 + lo]

#define LOADEA(t) { \
  const float* eab_ = ea + (size_t)((t) * 32 + lo) * 64; \
  _Pragma("unroll") for (int j = 0; j < 4; ++j) { \
    eareg[2 * j]     = *reinterpret_cast<const float4*>(eab_ + j * 16 + hi * 8); \
    eareg[2 * j + 1] = *reinterpret_cast<const float4*>(eab_ + j * 16 + hi * 8 + 4); \
  } }

#define LOADH2(NODE2) { \
  const unsigned short* hb_ = hbf + (size_t)(NODE2) * 64; \
  _Pragma("unroll") for (int k2 = 0; k2 < 4; ++k2) \
    h2reg[k2] = *reinterpret_cast<const bf16x8*>(hb_ + (2 * k2 + hi) * 8); }

#define ISSUE_H1(NODE, HBASE) { \
  _Pragma("unroll") for (int it = 0; it < 4; ++it) { \
    int r_ = it * 8 + l8; \
    int c_ = p ^ (r_ & 7); \
    int nd_ = __shfl(NODE, r_, 64); \
    async_copy16(hbf + (size_t)nd_ * 64 + c_ * 8, (HBASE) + it * 1024); \
  } }

  // ---- prologue ----
  int t = gw;
  if (t < ntiles) {
    int node2c = IDX2(t);
    int node1c = IDX1(t);
    LOADEA(t)
    LOADH2(node2c)
    ISSUE_H1(node1c, HA0)
    nodeN1 = IDX1(min(t + nwaves, tmax));
    WAITV(0);
  }

  int cur = 0;
  for (; t < ntiles; t += nwaves) {
    unsigned char* HAc = HA0 + cur * 4096;
    unsigned char* HAn = HA0 + (cur ^ 1) * 4096;
    const int eb  = t * 32;
    const int tn  = min(t + nwaves, tmax);
    const int tnn = min(t + 2 * nwaves, tmax);

    // h1(t) retired: exactly 22 ops issued after its batch (see header)
    WAITV(22);

    ISSUE_H1(nodeN1, HAn)               // [4]  h1(t+1) async
    int node1new = IDX1(tnn);           // [1]
    int node2new = IDX2(tn);            // [1]

    // ---- GEMM1: x^T = W1^T(128x192) @ concat^T ----
    f32x16 acc[4];
    #pragma unroll
    for (int m = 0; m < 4; ++m) acc[m] = (f32x16)0.0f;

    __builtin_amdgcn_s_setprio(1);
    #pragma unroll
    for (int kk = 0; kk < 12; ++kk) {
      bf16x8 bfr;
      if (kk < 4) {
        bfr = *reinterpret_cast<const bf16x8*>(
            HAc + lo * 128 + (((2 * kk + hi) ^ rsw) * 16));
      } else if (kk < 8) {
        bfr = h2reg[kk - 4];
      } else {
        float4 lo4 = eareg[(kk - 8) * 2];
        float4 hi4 = eareg[(kk - 8) * 2 + 1];
        union { bf16x8 v; unsigned u[4]; } tt;
        tt.u[0] = cvt_pk_bf16(lo4.x, lo4.y);
        tt.u[1] = cvt_pk_bf16(lo4.z, lo4.w);
        tt.u[2] = cvt_pk_bf16(hi4.x, hi4.y);
        tt.u[3] = cvt_pk_bf16(hi4.z, hi4.w);
        bfr = tt.v;
      }
      #pragma unroll
      for (int mt = 0; mt < 4; ++mt) {
        bf16x8 afr = *reinterpret_cast<const bf16x8*>(
            W1L + (size_t)(kk * 4 + mt) * 1024 + lane * 16);
        acc[mt] = __builtin_amdgcn_mfma_f32_32x32x16_bf16(afr, bfr, acc[mt], 0, 0, 0);
      }
    }
    __builtin_amdgcn_s_setprio(0);

    // prefetch t+1 inputs (overwrite eareg/h2reg — dead after GEMM1)
    LOADEA(tn)                          // [8]
    LOADH2(node2new)                    // [4]

    // ---- epilogue 1: bias(LDS) + softplus, packed bf16 in-register ----
    unsigned u0[16], u1[16];
    #pragma unroll
    for (int c = 0; c < 16; ++c) {
      int mt = c >> 2, g = c & 3;
      float4 bb = *reinterpret_cast<const float4*>(BL1 + mt * 32 + g * 8 + hi * 4);
      float s0 = shsp(acc[mt][g * 4 + 0] + bb.x);
      float s1 = shsp(acc[mt][g * 4 + 1] + bb.y);
      float s2 = shsp(acc[mt][g * 4 + 2] + bb.z);
      float s3 = shsp(acc[mt][g * 4 + 3] + bb.w);
      u0[c] = cvt_pk_bf16(s0, s1);
      u1[c] = cvt_pk_bf16(s2, s3);
    }

    // ---- half-exchange lane <-> lane^32 (R6-verified) -> GEMM2 B-frags ----
    unsigned pa[8][4];
    #pragma unroll
    for (int kk = 0; kk < 8; ++kk) {
      unsigned x0 = u0[2 * kk], y0 = u0[2 * kk + 1];
      unsigned x1 = u1[2 * kk], y1 = u1[2 * kk + 1];
      unsigned s0 = hi ? x0 : y0;
      unsigned s1 = hi ? x1 : y1;
      unsigned t0 = (unsigned)__shfl_xor((int)s0, 32, 64);
      unsigned t1 = (unsigned)__shfl_xor((int)s1, 32, 64);
      pa[kk][0] = hi ? t0 : x0;
      pa[kk][1] = hi ? t1 : x1;
      pa[kk][2] = hi ? y0 : t0;
      pa[kk][3] = hi ? y1 : t1;
    }

    // ---- GEMM2: out^T = W2^T(64x128) @ x; W2 frags from LDS ----
    f32x16 acc2[2];
    #pragma unroll
    for (int m = 0; m < 2; ++m) acc2[m] = (f32x16)0.0f;

    __builtin_amdgcn_s_setprio(1);
    #pragma unroll
    for (int kk = 0; kk < 8; ++kk) {
      union { bf16x8 v; unsigned u[4]; } tt;
      tt.u[0] = pa[kk][0];
      tt.u[1] = pa[kk][1];
      tt.u[2] = pa[kk][2];
      tt.u[3] = pa[kk][3];
      #pragma unroll
      for (int mt = 0; mt < 2; ++mt) {
        bf16x8 afr = *reinterpret_cast<const bf16x8*>(
            W2L + (size_t)(kk * 2 + mt) * 1024 + lane * 16);
        acc2[mt] = __builtin_amdgcn_mfma_f32_32x32x16_bf16(afr, tt.v, acc2[mt], 0, 0, 0);
      }
    }
    __builtin_amdgcn_s_setprio(0);

    // ---- epilogue 2 + stores: two 4K passes through HAc (h1 dead) ----
    #pragma unroll
    for (int mt = 0; mt < 2; ++mt) {
      #pragma unroll
      for (int g = 0; g < 4; ++g) {
        float4 bb = *reinterpret_cast<const float4*>(BL2 + mt * 32 + g * 8 + hi * 4);
        float4 o;
        o.x = acc2[mt][g * 4 + 0] + bb.x;
        o.y = acc2[mt][g * 4 + 1] + bb.y;
        o.z = acc2[mt][g * 4 + 2] + bb.z;
        o.w = acc2[mt][g * 4 + 3] + bb.w;
        int c = g * 2 + hi;                  // 16B chunk in 128B half-row
        *reinterpret_cast<float4*>(HAc + lo * 128 + ((c ^ rsw) * 16)) = o;
      }
      #pragma unroll
      for (int it = 0; it < 4; ++it) {       // [4] coalesced stores per pass
        int r = it * 8 + l8;
        float4 v = *reinterpret_cast<const float4*>(HAc + r * 128 + p * 16);
        int c = p ^ (r & 7);
        *reinterpret_cast<float4*>(
            out + (size_t)(eb + r) * 64 + mt * 32 + c * 4) = v;
      }
      // pass B's ds_writes ordered after pass A's ds_reads (in-order DS)
    }

    nodeN1 = node1new;
    cur ^= 1;
  }
}

extern "C" void kernel_launch(void* const* d_in, const int* in_sizes, int n_in,
                              void* d_out, int out_size, void* d_ws, size_t ws_size,
                              hipStream_t stream) {
  const float* h  = (const float*)d_in[0];
  const float* ea = (const float*)d_in[1];
  const int*  idx = (const int*)d_in[2];
  const float* W1 = (const float*)d_in[3];
  const float* b1 = (const float*)d_in[4];
  const float* W2 = (const float*)d_in[5];
  const float* b2 = (const float*)d_in[6];
  float* out = (float*)d_out;

  const int N = in_sizes[0] / 64;      // 50000
  const int E = in_sizes[1] / 64;      // 800000

  unsigned short* hbf = (unsigned short*)d_ws;                       // N*64 bf16
  size_t off1 = (size_t)N * 64 * 2;
  unsigned short* Wp1 = (unsigned short*)((char*)d_ws + off1);       // 24576 bf16
  unsigned short* Wp2 = Wp1 + 24576;                                 // contiguous

  int n4 = (N * 64) / 4;
  prep_h_kernel<<<(n4 + 255) / 256, 256, 0, stream>>>(h, hbf, n4);
  prep_w_kernel<<<16, 256, 0, stream>>>(W1, W2, Wp1, Wp2);

  int ntiles = E / 32;                  // 25000 wave-tiles
  edge_mlp_kernel<<<256, 512, 0, stream>>>(ea, idx, b1, b2, hbf, Wp1,
                                           out, E, ntiles);
}

// Round 16
// 121.581 us; speedup vs baseline: 2.1601x; 1.0024x over previous
//
#include <hip/hip_runtime.h>
#include <cstddef>
#include <cstdint>

typedef __attribute__((ext_vector_type(8))) short bf16x8;   // 8 bf16 = 4 VGPR
typedef __attribute__((ext_vector_type(16))) float f32x16;  // MFMA 32x32 acc

static constexpr float LN2 = 0.69314718055994530942f;
static constexpr float INV_LN2 = 1.44269504088896340736f;

__device__ __forceinline__ unsigned short f2bf(float f) {
  unsigned int u = __float_as_uint(f);
  u += 0x7fffu + ((u >> 16) & 1u);   // RNE
  return (unsigned short)(u >> 16);
}

__device__ __forceinline__ unsigned int cvt_pk_bf16(float a, float b) {
  unsigned int r;
  asm("v_cvt_pk_bf16_f32 %0, %1, %2" : "=v"(r) : "v"(a), "v"(b));
  return r;
}

__device__ __forceinline__ float hw_exp2(float x) {
  float r;
  asm("v_exp_f32 %0, %1" : "=v"(r) : "v"(x));
  return r;
}
__device__ __forceinline__ float hw_log2(float x) {
  float r;
  asm("v_log_f32 %0, %1" : "=v"(r) : "v"(x));
  return r;
}

// softplus(x)-ln2 = max(x,0)-ln2 + ln2*log2(1+2^(-|x|/ln2)); rel err ~1e-5
__device__ __forceinline__ float shsp(float x) {
  float t = hw_exp2(-fabsf(x) * INV_LN2);
  float l = hw_log2(1.0f + t);
  return fmaf(LN2, l, fmaxf(x, 0.0f) - LN2);
}

// async 16B global -> LDS (lane l writes lds + l*16)
__device__ __forceinline__ void async_copy16(const void* g, void* l) {
  __builtin_amdgcn_global_load_lds(
      (const __attribute__((address_space(1))) void*)g,
      (__attribute__((address_space(3))) void*)l, 16, 0, 0);
}

#define WAITV(N) asm volatile("s_waitcnt vmcnt(" #N ")" ::: "memory")

// ---- prep: h (N*64 f32) -> bf16 ----
__global__ void prep_h_kernel(const float* __restrict__ h,
                              unsigned short* __restrict__ hbf, int n4) {
  int i = blockIdx.x * 256 + threadIdx.x;
  if (i < n4) {
    float4 v = reinterpret_cast<const float4*>(h)[i];
    uint2 o;
    o.x = cvt_pk_bf16(v.x, v.y);
    o.y = cvt_pk_bf16(v.z, v.w);
    reinterpret_cast<uint2*>(hbf)[i] = o;
  }
}

// ---- prep: pack W1^T, W2^T into MFMA-fragment order (bf16), kk-major ----
// Wp1/Wp2 CONTIGUOUS in d_ws: chunks 0..3071 = W1, 3072..4095 = W2.
__global__ void prep_w_kernel(const float* __restrict__ W1,
                              const float* __restrict__ W2,
                              unsigned short* __restrict__ Wp1,
                              unsigned short* __restrict__ Wp2) {
  int j = blockIdx.x * 256 + threadIdx.x;
  if (j < 48 * 64) {
    int f  = j / 64;
    int l  = j % 64;
    int kk = f >> 2;
    int mt = f & 3;
    int col = mt * 32 + (l & 31);
    int kb  = kk * 16 + (l >> 5) * 8;
    #pragma unroll
    for (int i = 0; i < 8; ++i)
      Wp1[(size_t)j * 8 + i] = f2bf(W1[(size_t)(kb + i) * 128 + col]);
  } else if (j < 48 * 64 + 16 * 64) {
    int jj = j - 48 * 64;
    int f  = jj / 64;
    int l  = jj % 64;
    int kk = f >> 1;
    int mt = f & 1;
    int oc = mt * 32 + (l & 31);
    int kb = kk * 16 + (l >> 5) * 8;
    #pragma unroll
    for (int i = 0; i < 8; ++i)
      Wp2[(size_t)jj * 8 + i] = f2bf(W2[(size_t)(kb + i) * 64 + oc]);
  }
}

// ---- main fused kernel: 11 pipelined waves, W1+W2+biases in LDS ----
// 704 threads (11 waves, 2.75/SIMD), 1 block/CU. LDS 156,416B:
//   [0,48K) W1 frags; [48K,64K) W2 frags; [64K,64K+88K) 11 x 8K h1-dbuf
//   (4K/buffer: 32 rows x 128B, src-swizzled); [+88K,+768B) b1|b2 f32.
// Identical per-wave schedule to R15 (WAITV(22) exact anchor; counted ops
// per tile: H1[4] IDX1[1] IDX2[1] EA[8] H2[4] STa[4] STb[4]); only the
// wave count / W1-staging partition / bias offset changed.
__global__ __launch_bounds__(704, 1)
void edge_mlp_kernel(const float* __restrict__ ea,
                     const int* __restrict__ eidx,
                     const float* __restrict__ b1,
                     const float* __restrict__ b2,
                     const unsigned short* __restrict__ hbf,
                     const unsigned short* __restrict__ Wp1,
                     float* __restrict__ out,
                     int E, int ntiles) {
  __shared__ __align__(16) unsigned char LDS[156416];

  const int tid  = threadIdx.x;
  const int lane = tid & 63;
  const int w    = tid >> 6;          // 0..10
  const int lo   = lane & 31;
  const int hi   = lane >> 5;
  const int rsw  = lo & 7;
  const int l8   = lane >> 3;         // staging row-within-8
  const int p    = lane & 7;          // staging chunk position (8/row)

  unsigned char* W1L = LDS;                        // 48K: frags 0..47
  unsigned char* W2L = LDS + 49152;                // 16K: frags 0..15
  unsigned char* HA0 = LDS + 65536 + w * 8192;     // 2 x 4K dbuf
  float*         BL1 = reinterpret_cast<float*>(LDS + 155648);        // 128 f32
  float*         BL2 = reinterpret_cast<float*>(LDS + 155648 + 512);  // 64 f32

  // ---- stage W1+W2 into LDS once (64KB = 4096 chunks; Wp1||Wp2 contig) ----
  #pragma unroll
  for (int j = 0; j < 6; ++j) {
    int ch = j * 704 + w * 64;
    if (ch < 4096)
      async_copy16(Wp1 + (size_t)(ch + lane) * 8, LDS + ch * 16);
  }
  // ---- biases -> LDS (off the vmcnt path forever after) ----
  if (tid < 32) {
    float4 v = reinterpret_cast<const float4*>(b1)[tid];
    reinterpret_cast<float4*>(BL1)[tid] = v;
  } else if (tid < 48) {
    float4 v = reinterpret_cast<const float4*>(b2)[tid - 32];
    reinterpret_cast<float4*>(BL2)[tid - 32] = v;
  }
  __syncthreads();                      // once; drains vmcnt

  const int gw     = blockIdx.x * 11 + w;
  const int nwaves = gridDim.x * 11;
  const int tmax   = ntiles - 1;

  float4 eareg[8];
  bf16x8 h2reg[4];
  int nodeN1 = 0;

#define IDX1(t) eidx[(size_t)(t) * 32 + lo]
#define IDX2(t) eidx[(size_t)E + (size_t)(t) * 32 + lo]

#define LOADEA(t) { \
  const float* eab_ = ea + (size_t)((t) * 32 + lo) * 64; \
  _Pragma("unroll") for (int j = 0; j < 4; ++j) { \
    eareg[2 * j]     = *reinterpret_cast<const float4*>(eab_ + j * 16 + hi * 8); \
    eareg[2 * j + 1] = *reinterpret_cast<const float4*>(eab_ + j * 16 + hi * 8 + 4); \
  } }

#define LOADH2(NODE2) { \
  const unsigned short* hb_ = hbf + (size_t)(NODE2) * 64; \
  _Pragma("unroll") for (int k2 = 0; k2 < 4; ++k2) \
    h2reg[k2] = *reinterpret_cast<const bf16x8*>(hb_ + (2 * k2 + hi) * 8); }

#define ISSUE_H1(NODE, HBASE) { \
  _Pragma("unroll") for (int it = 0; it < 4; ++it) { \
    int r_ = it * 8 + l8; \
    int c_ = p ^ (r_ & 7); \
    int nd_ = __shfl(NODE, r_, 64); \
    async_copy16(hbf + (size_t)nd_ * 64 + c_ * 8, (HBASE) + it * 1024); \
  } }

  // ---- prologue ----
  int t = gw;
  if (t < ntiles) {
    int node2c = IDX2(t);
    int node1c = IDX1(t);
    LOADEA(t)
    LOADH2(node2c)
    ISSUE_H1(node1c, HA0)
    nodeN1 = IDX1(min(t + nwaves, tmax));
    WAITV(0);
  }

  int cur = 0;
  for (; t < ntiles; t += nwaves) {
    unsigned char* HAc = HA0 + cur * 4096;
    unsigned char* HAn = HA0 + (cur ^ 1) * 4096;
    const int eb  = t * 32;
    const int tn  = min(t + nwaves, tmax);
    const int tnn = min(t + 2 * nwaves, tmax);

    // h1(t) retired: exactly 22 vmem ops issued after its batch
    WAITV(22);

    ISSUE_H1(nodeN1, HAn)               // [4]  h1(t+1) async
    int node1new = IDX1(tnn);           // [1]
    int node2new = IDX2(tn);            // [1]

    // ---- GEMM1: x^T = W1^T(128x192) @ concat^T ----
    f32x16 acc[4];
    #pragma unroll
    for (int m = 0; m < 4; ++m) acc[m] = (f32x16)0.0f;

    __builtin_amdgcn_s_setprio(1);
    #pragma unroll
    for (int kk = 0; kk < 12; ++kk) {
      bf16x8 bfr;
      if (kk < 4) {
        bfr = *reinterpret_cast<const bf16x8*>(
            HAc + lo * 128 + (((2 * kk + hi) ^ rsw) * 16));
      } else if (kk < 8) {
        bfr = h2reg[kk - 4];
      } else {
        float4 lo4 = eareg[(kk - 8) * 2];
        float4 hi4 = eareg[(kk - 8) * 2 + 1];
        union { bf16x8 v; unsigned u[4]; } tt;
        tt.u[0] = cvt_pk_bf16(lo4.x, lo4.y);
        tt.u[1] = cvt_pk_bf16(lo4.z, lo4.w);
        tt.u[2] = cvt_pk_bf16(hi4.x, hi4.y);
        tt.u[3] = cvt_pk_bf16(hi4.z, hi4.w);
        bfr = tt.v;
      }
      #pragma unroll
      for (int mt = 0; mt < 4; ++mt) {
        bf16x8 afr = *reinterpret_cast<const bf16x8*>(
            W1L + (size_t)(kk * 4 + mt) * 1024 + lane * 16);
        acc[mt] = __builtin_amdgcn_mfma_f32_32x32x16_bf16(afr, bfr, acc[mt], 0, 0, 0);
      }
    }
    __builtin_amdgcn_s_setprio(0);

    // prefetch t+1 inputs (overwrite eareg/h2reg — dead after GEMM1)
    LOADEA(tn)                          // [8]
    LOADH2(node2new)                    // [4]

    // ---- epilogue 1: bias(LDS) + softplus, packed bf16 in-register ----
    unsigned u0[16], u1[16];
    #pragma unroll
    for (int c = 0; c < 16; ++c) {
      int mt = c >> 2, g = c & 3;
      float4 bb = *reinterpret_cast<const float4*>(BL1 + mt * 32 + g * 8 + hi * 4);
      float s0 = shsp(acc[mt][g * 4 + 0] + bb.x);
      float s1 = shsp(acc[mt][g * 4 + 1] + bb.y);
      float s2 = shsp(acc[mt][g * 4 + 2] + bb.z);
      float s3 = shsp(acc[mt][g * 4 + 3] + bb.w);
      u0[c] = cvt_pk_bf16(s0, s1);
      u1[c] = cvt_pk_bf16(s2, s3);
    }

    // ---- half-exchange lane <-> lane^32 (R6-verified) -> GEMM2 B-frags ----
    unsigned pa[8][4];
    #pragma unroll
    for (int kk = 0; kk < 8; ++kk) {
      unsigned x0 = u0[2 * kk], y0 = u0[2 * kk + 1];
      unsigned x1 = u1[2 * kk], y1 = u1[2 * kk + 1];
      unsigned s0 = hi ? x0 : y0;
      unsigned s1 = hi ? x1 : y1;
      unsigned t0 = (unsigned)__shfl_xor((int)s0, 32, 64);
      unsigned t1 = (unsigned)__shfl_xor((int)s1, 32, 64);
      pa[kk][0] = hi ? t0 : x0;
      pa[kk][1] = hi ? t1 : x1;
      pa[kk][2] = hi ? y0 : t0;
      pa[kk][3] = hi ? y1 : t1;
    }

    // ---- GEMM2: out^T = W2^T(64x128) @ x; W2 frags from LDS ----
    f32x16 acc2[2];
    #pragma unroll
    for (int m = 0; m < 2; ++m) acc2[m] = (f32x16)0.0f;

    __builtin_amdgcn_s_setprio(1);
    #pragma unroll
    for (int kk = 0; kk < 8; ++kk) {
      union { bf16x8 v; unsigned u[4]; } tt;
      tt.u[0] = pa[kk][0];
      tt.u[1] = pa[kk][1];
      tt.u[2] = pa[kk][2];
      tt.u[3] = pa[kk][3];
      #pragma unroll
      for (int mt = 0; mt < 2; ++mt) {
        bf16x8 afr = *reinterpret_cast<const bf16x8*>(
            W2L + (size_t)(kk * 2 + mt) * 1024 + lane * 16);
        acc2[mt] = __builtin_amdgcn_mfma_f32_32x32x16_bf16(afr, tt.v, acc2[mt], 0, 0, 0);
      }
    }
    __builtin_amdgcn_s_setprio(0);

    // ---- epilogue 2 + stores: two 4K passes through HAc (h1 dead) ----
    #pragma unroll
    for (int mt = 0; mt < 2; ++mt) {
      #pragma unroll
      for (int g = 0; g < 4; ++g) {
        float4 bb = *reinterpret_cast<const float4*>(BL2 + mt * 32 + g * 8 + hi * 4);
        float4 o;
        o.x = acc2[mt][g * 4 + 0] + bb.x;
        o.y = acc2[mt][g * 4 + 1] + bb.y;
        o.z = acc2[mt][g * 4 + 2] + bb.z;
        o.w = acc2[mt][g * 4 + 3] + bb.w;
        int c = g * 2 + hi;                  // 16B chunk in 128B half-row
        *reinterpret_cast<float4*>(HAc + lo * 128 + ((c ^ rsw) * 16)) = o;
      }
      #pragma unroll
      for (int it = 0; it < 4; ++it) {       // [4] coalesced stores per pass
        int r = it * 8 + l8;
        float4 v = *reinterpret_cast<const float4*>(HAc + r * 128 + p * 16);
        int c = p ^ (r & 7);
        *reinterpret_cast<float4*>(
            out + (size_t)(eb + r) * 64 + mt * 32 + c * 4) = v;
      }
      // pass B's ds_writes ordered after pass A's ds_reads (in-order DS)
    }

    nodeN1 = node1new;
    cur ^= 1;
  }
}

extern "C" void kernel_launch(void* const* d_in, const int* in_sizes, int n_in,
                              void* d_out, int out_size, void* d_ws, size_t ws_size,
                              hipStream_t stream) {
  const float* h  = (const float*)d_in[0];
  const float* ea = (const float*)d_in[1];
  const int*  idx = (const int*)d_in[2];
  const float* W1 = (const float*)d_in[3];
  const float* b1 = (const float*)d_in[4];
  const float* W2 = (const float*)d_in[5];
  const float* b2 = (const float*)d_in[6];
  float* out = (float*)d_out;

  const int N = in_sizes[0] / 64;      // 50000
  const int E = in_sizes[1] / 64;      // 800000

  unsigned short* hbf = (unsigned short*)d_ws;                       // N*64 bf16
  size_t off1 = (size_t)N * 64 * 2;
  unsigned short* Wp1 = (unsigned short*)((char*)d_ws + off1);       // 24576 bf16
  unsigned short* Wp2 = Wp1 + 24576;                                 // contiguous

  int n4 = (N * 64) / 4;
  prep_h_kernel<<<(n4 + 255) / 256, 256, 0, stream>>>(h, hbf, n4);
  prep_w_kernel<<<16, 256, 0, stream>>>(W1, W2, Wp1, Wp2);

  int ntiles = E / 32;                  // 25000 wave-tiles
  edge_mlp_kernel<<<256, 704, 0, stream>>>(ea, idx, b1, b2, hbf, Wp1,
                                           out, E, ntiles);
}